// Round 3
// baseline (1107.966 us; speedup 1.0000x reference)
//
#include <hip/hip_runtime.h>
#include <hip/hip_bf16.h>
#include <stdint.h>

// ---------------- problem constants ----------------
constexpr int NT = 8192;   // tokens (B*S)
constexpr int NE = 8;      // experts
constexpr int ND = 1024;   // d_model
constexpr int NH = 4096;   // hidden

constexpr int TM = 192;    // block tile M (2 waves of 96)
constexpr int TN = 192;    // block tile N
constexpr int BK = 64;     // K tile

typedef __attribute__((ext_vector_type(8)))  short short8;   // 8 bf16 (4 VGPRs)
typedef __attribute__((ext_vector_type(16))) float f32x16;   // 32x32 accumulator
typedef __attribute__((ext_vector_type(4)))  float f32x4;

// ---------------- workspace layout (bytes) ----------------
constexpr size_t O_XBF  = 0;                                   // x bf16 [NT][ND]
constexpr size_t O_WUPT = O_XBF  + (size_t)NT * ND * 2;        // w_up^T bf16 [E][H][D]
constexpr size_t O_WDNT = O_WUPT + (size_t)NE * NH * ND * 2;   // w_down^T bf16 [E][D][H]
constexpr size_t O_HBUF = O_WDNT + (size_t)NE * ND * NH * 2;   // hidden bf16 [NT*2][NH]
constexpr size_t O_STOK = O_HBUF + (size_t)NT * 2 * NH * 2;    // slot -> token
constexpr size_t O_SP   = O_STOK + (size_t)NT * 2 * 4;         // slot -> gate p
constexpr size_t O_TKE  = O_SP   + (size_t)NT * 2 * 4;         // token -> top2 experts
constexpr size_t O_TKP  = O_TKE  + (size_t)NT * 2 * 4;         // token -> top2 probs
constexpr size_t O_CTRL = O_TKP  + (size_t)NT * 2 * 4;
// ctrl: cnt[16]@0 fill[16]@64 probsum[8]@128 off[16]@192 ntiles[2]@256
constexpr size_t O_TLUP = O_CTRL + 272;                        // int[96]  tile list up
constexpr size_t O_TLDN = O_TLUP + 96 * 4;                     // int[112] tile list down (kpos-tagged)

__device__ __forceinline__ void gl_lds16(const void* g, void* l) {
  using GP = char __attribute__((address_space(1))) *;
  using LP = char __attribute__((address_space(3))) *;
  __builtin_amdgcn_global_load_lds((GP)(uintptr_t)g, (LP)(uint32_t)(uintptr_t)l, 16, 0, 0);
}

__device__ __forceinline__ float fast_gelu(float x) {
  float u  = 0.7978845608028654f * (x + 0.044715f * x * x * x);
  float ex = __expf(2.0f * u);
  float th = 1.0f - 2.0f / (ex + 1.0f);
  return 0.5f * x * (1.0f + th);
}

// ---------------- router: logits, softmax, top2, counts; also x->bf16 ----------------
__global__ __launch_bounds__(256) void moe_router(
    const float* __restrict__ x, const float* __restrict__ rw, const float* __restrict__ rb,
    __hip_bfloat16* __restrict__ xbf,
    float* __restrict__ probs_out, int* __restrict__ topk_e, float* __restrict__ topk_p,
    int* __restrict__ cnt_ek, float* __restrict__ probsum)
{
  __shared__ float ps[NE];
  __shared__ int cs[16];
  const int tid = threadIdx.x;
  if (tid < NE) ps[tid] = 0.f;
  if (tid < 16) cs[tid] = 0;
  __syncthreads();
  const int lane = tid & 63, wv = tid >> 6;
  for (int it = 0; it < 8; ++it) {
    const int t = blockIdx.x * 4 + wv + it * 1024;
    const float* xr = x + (size_t)t * ND;
    float acc[NE] = {};
#pragma unroll 4
    for (int j = 0; j < 16; ++j) {
      const int d = j * 64 + lane;
      const float xv = xr[d];
      xbf[(size_t)t * ND + d] = __float2bfloat16(xv);
      const float* w = rw + (size_t)d * NE;
#pragma unroll
      for (int ee = 0; ee < NE; ++ee) acc[ee] += xv * w[ee];
    }
#pragma unroll
    for (int ee = 0; ee < NE; ++ee)
#pragma unroll
      for (int off = 32; off >= 1; off >>= 1)
        acc[ee] += __shfl_down(acc[ee], off, 64);
    if (lane == 0) {
      float lg[NE];
#pragma unroll
      for (int ee = 0; ee < NE; ++ee) lg[ee] = acc[ee] + rb[ee];
      float mx = lg[0];
#pragma unroll
      for (int ee = 1; ee < NE; ++ee) mx = fmaxf(mx, lg[ee]);
      float s = 0.f, pe[NE];
#pragma unroll
      for (int ee = 0; ee < NE; ++ee) { pe[ee] = __expf(lg[ee] - mx); s += pe[ee]; }
      const float inv = 1.f / s;
#pragma unroll
      for (int ee = 0; ee < NE; ++ee) {
        const float pr = pe[ee] * inv;
        probs_out[(size_t)t * NE + ee] = pr;
        atomicAdd(&ps[ee], pr);
      }
      int i1 = 0; float l1 = lg[0];
#pragma unroll
      for (int ee = 1; ee < NE; ++ee) if (lg[ee] > l1) { l1 = lg[ee]; i1 = ee; }
      int i2 = 0; float l2 = -3.0e38f;
#pragma unroll
      for (int ee = 0; ee < NE; ++ee) if (ee != i1 && lg[ee] > l2) { l2 = lg[ee]; i2 = ee; }
      const float e2 = __expf(l2 - l1);
      const float dn = 1.f + e2;
      topk_e[t * 2]     = i1;  topk_e[t * 2 + 1] = i2;
      topk_p[t * 2]     = 1.f / dn;
      topk_p[t * 2 + 1] = e2 / dn;
      atomicAdd(&cs[i1 * 2], 1);
      atomicAdd(&cs[i2 * 2 + 1], 1);
    }
  }
  __syncthreads();
  if (tid < NE) atomicAdd(&probsum[tid], ps[tid]);
  if (tid < 16) atomicAdd(&cnt_ek[tid], cs[tid]);
}

// ---------------- offsets prefix + aux loss + tile lists ----------------
__global__ void moe_finalize(const int* __restrict__ cnt_ek, int* __restrict__ off_ek,
                             const float* __restrict__ probsum, float* __restrict__ aux_out,
                             int* __restrict__ ntiles, int* __restrict__ tl_up,
                             int* __restrict__ tl_dn)
{
  if (threadIdx.x == 0 && blockIdx.x == 0) {
    int run = 0;
    for (int i = 0; i < 16; ++i) { off_ek[i] = run; run += cnt_ek[i]; }
    float aux = 0.f;
    for (int ee = 0; ee < NE; ++ee) {
      float frac = (float)(cnt_ek[2 * ee] + cnt_ek[2 * ee + 1]) / (float)(NT * 2);
      aux += frac * (probsum[ee] / (float)NT);
    }
    aux_out[0] = (float)NE * aux * 0.01f;
    // up tiles: (e<<20)|mb, tile M = 192 over combined (e) bucket
    int ntu = 0;
    for (int e = 0; e < NE; ++e) {
      const int c = cnt_ek[2 * e] + cnt_ek[2 * e + 1];
      for (int mb = 0; mb < (c + TM - 1) / TM; ++mb) tl_up[ntu++] = (e << 20) | mb;
    }
    ntiles[0] = ntu;
    // down tiles combined over kpos: (e<<20)|(kp<<16)|mb
    int nt = 0;
    for (int kp = 0; kp < 2; ++kp)
      for (int e = 0; e < NE; ++e) {
        const int c = cnt_ek[2 * e + kp];
        for (int mb = 0; mb < (c + TM - 1) / TM; ++mb) tl_dn[nt++] = (e << 20) | (kp << 16) | mb;
      }
    ntiles[1] = nt;
  }
}

// ---------------- scatter tokens into (expert,k) buckets ----------------
__global__ __launch_bounds__(256) void moe_scatter(
    const int* __restrict__ topk_e, const float* __restrict__ topk_p,
    const int* __restrict__ off_ek, int* __restrict__ fill_ek,
    int* __restrict__ slot_token, float* __restrict__ slot_p)
{
  const int t = blockIdx.x * 256 + threadIdx.x;
  if (t >= NT) return;
#pragma unroll
  for (int k = 0; k < 2; ++k) {
    const int ee = topk_e[t * 2 + k];
    const int id = ee * 2 + k;
    const int r = atomicAdd(&fill_ek[id], 1);
    const int slot = off_ek[id] + r;
    slot_token[slot] = t;
    slot_p[slot] = topk_p[t * 2 + k];
  }
}

// ---------------- transpose+cast: in fp32 [E][A][B] -> out bf16 [E][B][A] ----------------
__global__ __launch_bounds__(256) void moe_transpose_cast(
    const float* __restrict__ in, __hip_bfloat16* __restrict__ outp, int Adim, int Bdim)
{
  __shared__ unsigned short tile[64 * 66];
  const int e = blockIdx.z;
  const int b0 = blockIdx.x * 64, a0 = blockIdx.y * 64;
  const float* ip = in + (size_t)e * Adim * Bdim + (size_t)a0 * Bdim + b0;
  const int c4 = (threadIdx.x & 15) * 4;
  const int r0 = threadIdx.x >> 4;
#pragma unroll
  for (int i = 0; i < 4; ++i) {
    const int r = r0 + i * 16;
    const float4 v = *(const float4*)(ip + (size_t)r * Bdim + c4);
    ushort4 u;
    u.x = __hip_bfloat16_raw(__float2bfloat16(v.x)).x;
    u.y = __hip_bfloat16_raw(__float2bfloat16(v.y)).x;
    u.z = __hip_bfloat16_raw(__float2bfloat16(v.z)).x;
    u.w = __hip_bfloat16_raw(__float2bfloat16(v.w)).x;
    *(ushort4*)&tile[r * 66 + c4] = u;
  }
  __syncthreads();
  unsigned short* op = (unsigned short*)outp + (size_t)e * Bdim * Adim + (size_t)b0 * Adim + a0;
  const int cc  = threadIdx.x >> 2;
  const int rr0 = (threadIdx.x & 3) * 16;
  unsigned short u[16];
#pragma unroll
  for (int i = 0; i < 16; ++i) u[i] = tile[(rr0 + i) * 66 + cc];
  *(short8*)(op + (size_t)cc * Adim + rr0)     = *(short8*)&u[0];
  *(short8*)(op + (size_t)cc * Adim + rr0 + 8) = *(short8*)&u[8];
}

// ---------------- grouped GEMM 1: H = gelu(X_sel @ w_up + b_up) ----------------
// 192x192 tile, 4 waves (2x2 of 96x96), mfma_32x32x16_bf16, BK=64.
// LDS: global-side chunk swizzle c^(row&7); linear lane slots -> conflict-free b128 reads.
__global__ __launch_bounds__(256, 2) void moe_gemm_up(
    const __hip_bfloat16* __restrict__ xbf,
    const __hip_bfloat16* __restrict__ wupT,   // [E][H][D]
    const float* __restrict__ b_up,
    const int* __restrict__ slot_token,
    const int* __restrict__ cnt_ek, const int* __restrict__ off_ek,
    const int* __restrict__ ntiles, const int* __restrict__ tl_up,
    __hip_bfloat16* __restrict__ hbuf)          // [NT*2][NH]
{
  if ((int)blockIdx.y >= ntiles[0]) return;
  const int tl = tl_up[blockIdx.y];
  const int e = tl >> 20, mb = tl & 0xffff;
  const int cnt = cnt_ek[2 * e] + cnt_ek[2 * e + 1];
  const int base = off_ek[2 * e];
  const int m0 = mb * TM;
  const int n0 = blockIdx.x * TN;
  const int valid = (cnt - m0 < TM) ? (cnt - m0) : TM;

  __shared__ __align__(16) __hip_bfloat16 As[TM * BK];   // 24 KB
  __shared__ __align__(16) __hip_bfloat16 Bs[TN * BK];   // 24 KB

  const int tid = threadIdx.x;
  const int lane = tid & 63, wv = tid >> 6;

  // staging: TM*8 = 1536 chunks each; 6 per thread. LDS slot = linear (chunk ci -> byte ci*16);
  // global chunk = (ci&7) ^ (row&7)  => LDS slot s of row r holds global chunk s^(r&7).
  const __hip_bfloat16* aptr[6];
  const __hip_bfloat16* bptr[6];
#pragma unroll
  for (int j = 0; j < 6; ++j) {
    const int ci = tid + 256 * j;
    const int row = ci >> 3;
    const int kc = (((ci & 7) ^ (row & 7))) * 8;
    int sr = m0 + row; if (sr >= cnt) sr = cnt - 1;
    aptr[j] = xbf + (size_t)slot_token[base + sr] * ND + kc;
    int br = n0 + row; if (br >= NH) br = NH - 1;
    bptr[j] = wupT + ((size_t)e * NH + br) * ND + kc;
  }
  char* lA = (char*)As + tid * 16;
  char* lB = (char*)Bs + tid * 16;

  const int wm = (wv >> 1) * 96, wn = (wv & 1) * 96;
  const int l31 = lane & 31, h = lane >> 5, swz = l31 & 7;
  const int arb = (wm + l31) * (BK * 2);
  const int brb = (wn + l31) * (BK * 2);

  f32x16 acc[3][3] = {};

  for (int kk = 0; kk < ND; kk += BK) {
    __syncthreads();
#pragma unroll
    for (int j = 0; j < 6; ++j) { gl_lds16(aptr[j], lA + j * 4096); aptr[j] += BK; }
#pragma unroll
    for (int j = 0; j < 6; ++j) { gl_lds16(bptr[j], lB + j * 4096); bptr[j] += BK; }
    __syncthreads();
#pragma unroll
    for (int s = 0; s < 4; ++s) {
      const int sl = ((((s << 1) | h) ^ swz) << 4);
      short8 af[3], bfr[3];
#pragma unroll
      for (int i = 0; i < 3; ++i) af[i]  = *(const short8*)((const char*)As + arb + i * 4096 + sl);
#pragma unroll
      for (int i = 0; i < 3; ++i) bfr[i] = *(const short8*)((const char*)Bs + brb + i * 4096 + sl);
#pragma unroll
      for (int mt = 0; mt < 3; ++mt)
#pragma unroll
        for (int nt = 0; nt < 3; ++nt)
          acc[mt][nt] = __builtin_amdgcn_mfma_f32_32x32x16_bf16(af[mt], bfr[nt], acc[mt][nt], 0, 0, 0);
    }
  }

  float bias[3];
#pragma unroll
  for (int nt = 0; nt < 3; ++nt) {
    const int col = n0 + wn + nt * 32 + l31;
    bias[nt] = (col < NH) ? b_up[e * NH + col] : 0.f;
  }
#pragma unroll
  for (int mt = 0; mt < 3; ++mt) {
#pragma unroll
    for (int r = 0; r < 16; ++r) {
      const int rowl = (r & 3) + ((r >> 2) << 3) + (h << 2);
      const int row = wm + mt * 32 + rowl;
      if (row < valid) {
        const size_t rbase = (size_t)(base + m0 + row) * NH;
#pragma unroll
        for (int nt = 0; nt < 3; ++nt) {
          const int col = n0 + wn + nt * 32 + l31;
          if (col < NH)
            hbuf[rbase + col] = __float2bfloat16(fast_gelu(acc[mt][nt][r] + bias[nt]));
        }
      }
    }
  }
}

// ---------------- grouped GEMM 2: out += p * (H @ w_down + b_down) ----------------
// single launch over kpos-tagged tile list; out zero-initialized; fp32 atomicAdd
// (exactly 2 addends per element -> deterministic).
__global__ __launch_bounds__(256, 2) void moe_gemm_down(
    const __hip_bfloat16* __restrict__ hbuf,
    const __hip_bfloat16* __restrict__ wdnT,   // [E][D][H]
    const float* __restrict__ b_down,
    const int* __restrict__ slot_token, const float* __restrict__ slot_p,
    const int* __restrict__ cnt_ek, const int* __restrict__ off_ek,
    const int* __restrict__ ntiles, const int* __restrict__ tl_dn,
    float* __restrict__ out)
{
  if ((int)blockIdx.y >= ntiles[1]) return;
  const int tl = tl_dn[blockIdx.y];
  const int e = tl >> 20, kp = (tl >> 16) & 0xF, mb = tl & 0xffff;
  const int id = 2 * e + kp;
  const int cnt = cnt_ek[id];
  const int base = off_ek[id];
  const int m0 = mb * TM;
  const int n0 = blockIdx.x * TN;
  const int valid = (cnt - m0 < TM) ? (cnt - m0) : TM;

  __shared__ __align__(16) __hip_bfloat16 As[TM * BK];
  __shared__ __align__(16) __hip_bfloat16 Bs[TN * BK];

  const int tid = threadIdx.x;
  const int lane = tid & 63, wv = tid >> 6;

  const __hip_bfloat16* aptr[6];
  const __hip_bfloat16* bptr[6];
#pragma unroll
  for (int j = 0; j < 6; ++j) {
    const int ci = tid + 256 * j;
    const int row = ci >> 3;
    const int kc = (((ci & 7) ^ (row & 7))) * 8;
    int sr = m0 + row; if (sr >= cnt) sr = cnt - 1;
    aptr[j] = hbuf + (size_t)(base + sr) * NH + kc;
    int br = n0 + row; if (br >= ND) br = ND - 1;
    bptr[j] = wdnT + ((size_t)e * ND + br) * NH + kc;
  }
  char* lA = (char*)As + tid * 16;
  char* lB = (char*)Bs + tid * 16;

  const int wm = (wv >> 1) * 96, wn = (wv & 1) * 96;
  const int l31 = lane & 31, h = lane >> 5, swz = l31 & 7;
  const int arb = (wm + l31) * (BK * 2);
  const int brb = (wn + l31) * (BK * 2);

  f32x16 acc[3][3] = {};

  for (int kk = 0; kk < NH; kk += BK) {
    __syncthreads();
#pragma unroll
    for (int j = 0; j < 6; ++j) { gl_lds16(aptr[j], lA + j * 4096); aptr[j] += BK; }
#pragma unroll
    for (int j = 0; j < 6; ++j) { gl_lds16(bptr[j], lB + j * 4096); bptr[j] += BK; }
    __syncthreads();
#pragma unroll
    for (int s = 0; s < 4; ++s) {
      const int sl = ((((s << 1) | h) ^ swz) << 4);
      short8 af[3], bfr[3];
#pragma unroll
      for (int i = 0; i < 3; ++i) af[i]  = *(const short8*)((const char*)As + arb + i * 4096 + sl);
#pragma unroll
      for (int i = 0; i < 3; ++i) bfr[i] = *(const short8*)((const char*)Bs + brb + i * 4096 + sl);
#pragma unroll
      for (int mt = 0; mt < 3; ++mt)
#pragma unroll
        for (int nt = 0; nt < 3; ++nt)
          acc[mt][nt] = __builtin_amdgcn_mfma_f32_32x32x16_bf16(af[mt], bfr[nt], acc[mt][nt], 0, 0, 0);
    }
  }

  float bias[3];
#pragma unroll
  for (int nt = 0; nt < 3; ++nt) {
    const int col = n0 + wn + nt * 32 + l31;
    bias[nt] = (col < ND) ? b_down[e * ND + col] : 0.f;
  }
#pragma unroll
  for (int mt = 0; mt < 3; ++mt) {
#pragma unroll
    for (int r = 0; r < 16; ++r) {
      const int rowl = (r & 3) + ((r >> 2) << 3) + (h << 2);
      const int row = wm + mt * 32 + rowl;
      if (row < valid) {
        const int slot = base + m0 + row;
        const int tok = slot_token[slot];
        const float p = slot_p[slot];
        const size_t obase = (size_t)tok * ND;
#pragma unroll
        for (int nt = 0; nt < 3; ++nt) {
          const int col = n0 + wn + nt * 32 + l31;
          if (col < ND)
            atomicAdd(&out[obase + col], (acc[mt][nt][r] + bias[nt]) * p);
        }
      }
    }
  }
}

// ---------------- launch ----------------
extern "C" void kernel_launch(void* const* d_in, const int* in_sizes, int n_in,
                              void* d_out, int out_size, void* d_ws, size_t ws_size,
                              hipStream_t stream) {
  (void)in_sizes; (void)n_in; (void)out_size; (void)ws_size;
  const float* x   = (const float*)d_in[0];
  const float* rw  = (const float*)d_in[1];
  const float* rb  = (const float*)d_in[2];
  const float* wup = (const float*)d_in[3];
  const float* bup = (const float*)d_in[4];
  const float* wdn = (const float*)d_in[5];
  const float* bdn = (const float*)d_in[6];
  float* out = (float*)d_out;

  char* ws = (char*)d_ws;
  __hip_bfloat16* xbf  = (__hip_bfloat16*)(ws + O_XBF);
  __hip_bfloat16* wupT = (__hip_bfloat16*)(ws + O_WUPT);
  __hip_bfloat16* wdnT = (__hip_bfloat16*)(ws + O_WDNT);
  __hip_bfloat16* hbuf = (__hip_bfloat16*)(ws + O_HBUF);
  int*   slot_token = (int*)(ws + O_STOK);
  float* slot_p     = (float*)(ws + O_SP);
  int*   topk_e     = (int*)(ws + O_TKE);
  float* topk_p     = (float*)(ws + O_TKP);
  int*   cnt_ek  = (int*)(ws + O_CTRL);
  int*   fill_ek = (int*)(ws + O_CTRL + 64);
  float* probsum = (float*)(ws + O_CTRL + 128);
  int*   off_ek  = (int*)(ws + O_CTRL + 192);
  int*   ntiles  = (int*)(ws + O_CTRL + 256);
  int*   tl_up   = (int*)(ws + O_TLUP);
  int*   tl_dn   = (int*)(ws + O_TLDN);

  hipMemsetAsync(ws + O_CTRL, 0, 272, stream);
  hipMemsetAsync(out, 0, (size_t)NT * ND * sizeof(float), stream);  // for down-GEMM atomicAdd

  // weight transposes (independent of router)
  moe_transpose_cast<<<dim3(NH / 64, ND / 64, NE), 256, 0, stream>>>(wup, wupT, ND, NH);
  moe_transpose_cast<<<dim3(ND / 64, NH / 64, NE), 256, 0, stream>>>(wdn, wdnT, NH, ND);

  // router (+ x->bf16), aux/offsets/tile-lists, scatter
  moe_router<<<256, 256, 0, stream>>>(x, rw, rb, xbf, out + (size_t)NT * ND + 1,
                                      topk_e, topk_p, cnt_ek, probsum);
  moe_finalize<<<1, 64, 0, stream>>>(cnt_ek, off_ek, probsum, out + (size_t)NT * ND,
                                     ntiles, tl_up, tl_dn);
  moe_scatter<<<NT / 256, 256, 0, stream>>>(topk_e, topk_p, off_ek, fill_ek, slot_token, slot_p);

  // grouped GEMMs (exact tile-list grids; blocks early-exit past device-side tile counts)
  moe_gemm_up<<<dim3((NH + TN - 1) / TN, 96, 1), 256, 0, stream>>>(
      xbf, wupT, bup, slot_token, cnt_ek, off_ek, ntiles, tl_up, hbuf);
  moe_gemm_down<<<dim3((ND + TN - 1) / TN, 112, 1), 256, 0, stream>>>(
      hbuf, wdnT, bdn, slot_token, slot_p, cnt_ek, off_ek, ntiles, tl_dn, out);
}

// Round 4
// 913.705 us; speedup vs baseline: 1.2126x; 1.2126x over previous
//
#include <hip/hip_runtime.h>
#include <hip/hip_bf16.h>
#include <stdint.h>

// ---------------- problem constants ----------------
constexpr int NT = 8192;   // tokens (B*S)
constexpr int NE = 8;      // experts
constexpr int ND = 1024;   // d_model
constexpr int NH = 4096;   // hidden

constexpr int TM = 128;    // block tile M
constexpr int TN = 256;    // block tile N (8 waves: 2x4 of 64x64)
constexpr int BK = 32;     // K tile

typedef __attribute__((ext_vector_type(8))) short short8;  // 8 bf16 (4 VGPRs)
typedef __attribute__((ext_vector_type(4))) float f32x4;

// ---------------- workspace layout (bytes) ----------------
constexpr size_t O_XBF  = 0;                                   // x bf16 [NT][ND]
constexpr size_t O_WUPT = O_XBF  + (size_t)NT * ND * 2;        // w_up^T bf16 [E][H][D]
constexpr size_t O_WDNT = O_WUPT + (size_t)NE * NH * ND * 2;   // w_down^T bf16 [E][D][H]
constexpr size_t O_HBUF = O_WDNT + (size_t)NE * ND * NH * 2;   // hidden bf16 [NT*2][NH]
constexpr size_t O_STOK = O_HBUF + (size_t)NT * 2 * NH * 2;    // slot -> token
constexpr size_t O_SP   = O_STOK + (size_t)NT * 2 * 4;         // slot -> gate p
constexpr size_t O_TKE  = O_SP   + (size_t)NT * 2 * 4;         // token -> top2 experts
constexpr size_t O_TKP  = O_TKE  + (size_t)NT * 2 * 4;         // token -> top2 probs
constexpr size_t O_CTRL = O_TKP  + (size_t)NT * 2 * 4;
// ctrl: cnt[16]@0 fill[16]@64 probsum[8]@128 off[16]@192 ntiles[2]@256
constexpr size_t O_TLUP = O_CTRL + 272;                        // int[160] tile list up
constexpr size_t O_TLDN = O_TLUP + 160 * 4;                    // int[160] tile list down

__device__ __forceinline__ void gl_lds16(const void* g, void* l) {
  using GP = char __attribute__((address_space(1))) *;
  using LP = char __attribute__((address_space(3))) *;
  __builtin_amdgcn_global_load_lds((GP)(uintptr_t)g, (LP)(uint32_t)(uintptr_t)l, 16, 0, 0);
}

__device__ __forceinline__ float fast_gelu(float x) {
  float u  = 0.7978845608028654f * (x + 0.044715f * x * x * x);
  float ex = __expf(2.0f * u);
  float th = 1.0f - 2.0f / (ex + 1.0f);
  return 0.5f * x * (1.0f + th);
}

// ---------------- router: logits, softmax, top2, counts; also x->bf16 ----------------
__global__ __launch_bounds__(256) void moe_router(
    const float* __restrict__ x, const float* __restrict__ rw, const float* __restrict__ rb,
    __hip_bfloat16* __restrict__ xbf,
    float* __restrict__ probs_out, int* __restrict__ topk_e, float* __restrict__ topk_p,
    int* __restrict__ cnt_ek, float* __restrict__ probsum)
{
  __shared__ float ps[NE];
  __shared__ int cs[16];
  const int tid = threadIdx.x;
  if (tid < NE) ps[tid] = 0.f;
  if (tid < 16) cs[tid] = 0;
  __syncthreads();
  const int lane = tid & 63, wv = tid >> 6;
  for (int it = 0; it < 8; ++it) {
    const int t = blockIdx.x * 4 + wv + it * 1024;
    const float* xr = x + (size_t)t * ND;
    float acc[NE] = {};
#pragma unroll 4
    for (int j = 0; j < 16; ++j) {
      const int d = j * 64 + lane;
      const float xv = xr[d];
      xbf[(size_t)t * ND + d] = __float2bfloat16(xv);
      const float* w = rw + (size_t)d * NE;
#pragma unroll
      for (int ee = 0; ee < NE; ++ee) acc[ee] += xv * w[ee];
    }
#pragma unroll
    for (int ee = 0; ee < NE; ++ee)
#pragma unroll
      for (int off = 32; off >= 1; off >>= 1)
        acc[ee] += __shfl_down(acc[ee], off, 64);
    if (lane == 0) {
      float lg[NE];
#pragma unroll
      for (int ee = 0; ee < NE; ++ee) lg[ee] = acc[ee] + rb[ee];
      float mx = lg[0];
#pragma unroll
      for (int ee = 1; ee < NE; ++ee) mx = fmaxf(mx, lg[ee]);
      float s = 0.f, pe[NE];
#pragma unroll
      for (int ee = 0; ee < NE; ++ee) { pe[ee] = __expf(lg[ee] - mx); s += pe[ee]; }
      const float inv = 1.f / s;
#pragma unroll
      for (int ee = 0; ee < NE; ++ee) {
        const float pr = pe[ee] * inv;
        probs_out[(size_t)t * NE + ee] = pr;
        atomicAdd(&ps[ee], pr);
      }
      int i1 = 0; float l1 = lg[0];
#pragma unroll
      for (int ee = 1; ee < NE; ++ee) if (lg[ee] > l1) { l1 = lg[ee]; i1 = ee; }
      int i2 = 0; float l2 = -3.0e38f;
#pragma unroll
      for (int ee = 0; ee < NE; ++ee) if (ee != i1 && lg[ee] > l2) { l2 = lg[ee]; i2 = ee; }
      const float e2 = __expf(l2 - l1);
      const float dn = 1.f + e2;
      topk_e[t * 2]     = i1;  topk_e[t * 2 + 1] = i2;
      topk_p[t * 2]     = 1.f / dn;
      topk_p[t * 2 + 1] = e2 / dn;
      atomicAdd(&cs[i1 * 2], 1);
      atomicAdd(&cs[i2 * 2 + 1], 1);
    }
  }
  __syncthreads();
  if (tid < NE) atomicAdd(&probsum[tid], ps[tid]);
  if (tid < 16) atomicAdd(&cnt_ek[tid], cs[tid]);
}

// ---------------- offsets prefix + aux loss + tile lists (lane-parallel writes) ----------
__global__ void moe_finalize(const int* __restrict__ cnt_ek, int* __restrict__ off_ek,
                             const float* __restrict__ probsum, float* __restrict__ aux_out,
                             int* __restrict__ ntiles, int* __restrict__ tl_up,
                             int* __restrict__ tl_dn)
{
  __shared__ int c[16], off[16], uoff[8], ucnt[8], doff[16], dcnt[16];
  const int tid = threadIdx.x;
  if (tid < 16) c[tid] = cnt_ek[tid];
  __syncthreads();
  if (tid == 0) {
    int run = 0;
    for (int i = 0; i < 16; ++i) { off[i] = run; run += c[i]; }
    int ur = 0;
    for (int e = 0; e < NE; ++e) {
      ucnt[e] = (c[2 * e] + c[2 * e + 1] + TM - 1) / TM;
      uoff[e] = ur; ur += ucnt[e];
    }
    ntiles[0] = ur;
    int dr = 0;
    for (int i = 0; i < 16; ++i) {
      dcnt[i] = (c[i] + TM - 1) / TM;
      doff[i] = dr; dr += dcnt[i];
    }
    ntiles[1] = dr;
    float aux = 0.f;
    for (int e = 0; e < NE; ++e) {
      float frac = (float)(c[2 * e] + c[2 * e + 1]) / (float)(NT * 2);
      aux += frac * (probsum[e] / (float)NT);
    }
    aux_out[0] = (float)NE * aux * 0.01f;
  }
  __syncthreads();
  if (tid < 16) off_ek[tid] = off[tid];
  if (tid < 8)
    for (int mb = 0; mb < ucnt[tid]; ++mb) tl_up[uoff[tid] + mb] = (tid << 16) | mb;
  if (tid >= 32 && tid < 48) {
    const int i = tid - 32;
    for (int mb = 0; mb < dcnt[i]; ++mb) tl_dn[doff[i] + mb] = (i << 16) | mb;
  }
}

// ---------------- scatter: per-block LDS histogram, 16 global atomics/block ----------
__global__ __launch_bounds__(256) void moe_scatter(
    const int* __restrict__ topk_e, const float* __restrict__ topk_p,
    const int* __restrict__ off_ek, int* __restrict__ fill_ek,
    int* __restrict__ slot_token, float* __restrict__ slot_p)
{
  __shared__ int lc[16], gb[16], offs[16];
  const int tid = threadIdx.x;
  if (tid < 16) lc[tid] = 0;
  __syncthreads();
  const int t = blockIdx.x * 256 + tid;
  const int id0 = topk_e[t * 2] * 2;
  const int id1 = topk_e[t * 2 + 1] * 2 + 1;
  atomicAdd(&lc[id0], 1);
  atomicAdd(&lc[id1], 1);
  __syncthreads();
  if (tid < 16) {
    gb[tid] = atomicAdd(&fill_ek[tid], lc[tid]);
    offs[tid] = off_ek[tid];
    lc[tid] = 0;
  }
  __syncthreads();
  {
    const int r = atomicAdd(&lc[id0], 1);
    const int slot = offs[id0] + gb[id0] + r;
    slot_token[slot] = t;
    slot_p[slot] = topk_p[t * 2];
  }
  {
    const int r = atomicAdd(&lc[id1], 1);
    const int slot = offs[id1] + gb[id1] + r;
    slot_token[slot] = t;
    slot_p[slot] = topk_p[t * 2 + 1];
  }
}

// ---------------- transpose+cast: in fp32 [E][A][B] -> out bf16 [E][B][A] ----------------
__global__ __launch_bounds__(256) void moe_transpose_cast(
    const float* __restrict__ in, __hip_bfloat16* __restrict__ outp, int Adim, int Bdim)
{
  __shared__ unsigned short tile[64 * 66];
  const int e = blockIdx.z;
  const int b0 = blockIdx.x * 64, a0 = blockIdx.y * 64;
  const float* ip = in + (size_t)e * Adim * Bdim + (size_t)a0 * Bdim + b0;
  const int c4 = (threadIdx.x & 15) * 4;
  const int r0 = threadIdx.x >> 4;
#pragma unroll
  for (int i = 0; i < 4; ++i) {
    const int r = r0 + i * 16;
    const float4 v = *(const float4*)(ip + (size_t)r * Bdim + c4);
    ushort4 u;
    u.x = __hip_bfloat16_raw(__float2bfloat16(v.x)).x;
    u.y = __hip_bfloat16_raw(__float2bfloat16(v.y)).x;
    u.z = __hip_bfloat16_raw(__float2bfloat16(v.z)).x;
    u.w = __hip_bfloat16_raw(__float2bfloat16(v.w)).x;
    *(ushort4*)&tile[r * 66 + c4] = u;
  }
  __syncthreads();
  unsigned short* op = (unsigned short*)outp + (size_t)e * Bdim * Adim + (size_t)b0 * Adim + a0;
  const int cc  = threadIdx.x >> 2;
  const int rr0 = (threadIdx.x & 3) * 16;
  unsigned short u[16];
#pragma unroll
  for (int i = 0; i < 16; ++i) u[i] = tile[(rr0 + i) * 66 + cc];
  *(short8*)(op + (size_t)cc * Adim + rr0)     = *(short8*)&u[0];
  *(short8*)(op + (size_t)cc * Adim + rr0 + 8) = *(short8*)&u[8];
}

// ---------------- grouped GEMM 1: H = gelu(X_sel @ w_up + b_up) ----------------
// 128x256 tile, 8 waves (2x4 of 64x64), 16x16x32 bf16 MFMA, BK=32.
// LDS chunk swizzle (round-1/2 pattern, measured 0 conflicts): slot (row,c) holds
// global chunk c ^ ((row>>1)&3); 64 B row stride.
__global__ __launch_bounds__(512, 4) void moe_gemm_up(
    const __hip_bfloat16* __restrict__ xbf,
    const __hip_bfloat16* __restrict__ wupT,   // [E][H][D]
    const float* __restrict__ b_up,
    const int* __restrict__ slot_token,
    const int* __restrict__ cnt_ek, const int* __restrict__ off_ek,
    const int* __restrict__ ntiles, const int* __restrict__ tl_up,
    __hip_bfloat16* __restrict__ hbuf)          // [NT*2][NH]
{
  if ((int)blockIdx.y >= ntiles[0]) return;
  const int tl = tl_up[blockIdx.y];
  const int e = tl >> 16, mb = tl & 0xffff;
  const int cnt = cnt_ek[2 * e] + cnt_ek[2 * e + 1];
  const int base = off_ek[2 * e];
  const int m0 = mb * TM;
  const int n0 = blockIdx.x * TN;
  const int valid = (cnt - m0 < TM) ? (cnt - m0) : TM;

  __shared__ __align__(16) __hip_bfloat16 As[TM * BK];   // 8 KB
  __shared__ __align__(16) __hip_bfloat16 Bs[TN * BK];   // 16 KB

  const int tid = threadIdx.x;
  const int lane = tid & 63, wv = tid >> 6;

  // A: 512 chunks (1/thread); B: 1024 chunks (2/thread)
  const int raA = tid >> 2;
  const int kcA = ((tid & 3) ^ ((raA >> 1) & 3)) * 8;
  int srA = m0 + raA; if (srA >= cnt) srA = cnt - 1;
  const __hip_bfloat16* ga = xbf + (size_t)slot_token[base + srA] * ND + kcA;
  const __hip_bfloat16* gb[2];
#pragma unroll
  for (int j = 0; j < 2; ++j) {
    const int ci = tid + 512 * j;
    const int row = ci >> 2;
    const int kc = ((ci & 3) ^ ((row >> 1) & 3)) * 8;
    gb[j] = wupT + ((size_t)e * NH + n0 + row) * ND + kc;
  }
  char* lA = (char*)As + tid * 16;
  char* lB = (char*)Bs + tid * 16;

  const int wm = (wv >> 2) * 64, wn = (wv & 3) * 64;
  const int l15 = lane & 15, q = lane >> 4;
  const int ssw = (q ^ ((l15 >> 1) & 3)) * 16;
  const char* rA = (const char*)As + (wm + l15) * 64 + ssw;
  const char* rB = (const char*)Bs + (wn + l15) * 64 + ssw;

  f32x4 acc[4][4] = {};

  for (int kk = 0; kk < ND; kk += BK) {
    __syncthreads();
    gl_lds16(ga + kk, lA);
    gl_lds16(gb[0] + kk, lB);
    gl_lds16(gb[1] + kk, lB + 8192);
    __syncthreads();
    short8 af[4], bfr[4];
#pragma unroll
    for (int i = 0; i < 4; ++i) af[i]  = *(const short8*)(rA + i * 1024);
#pragma unroll
    for (int i = 0; i < 4; ++i) bfr[i] = *(const short8*)(rB + i * 1024);
#pragma unroll
    for (int mt = 0; mt < 4; ++mt)
#pragma unroll
      for (int nt = 0; nt < 4; ++nt)
        acc[mt][nt] = __builtin_amdgcn_mfma_f32_16x16x32_bf16(af[mt], bfr[nt], acc[mt][nt], 0, 0, 0);
  }

  float bias[4];
#pragma unroll
  for (int nt = 0; nt < 4; ++nt) bias[nt] = b_up[e * NH + n0 + wn + nt * 16 + l15];
#pragma unroll
  for (int mt = 0; mt < 4; ++mt) {
#pragma unroll
    for (int rr = 0; rr < 4; ++rr) {
      const int row = wm + mt * 16 + q * 4 + rr;
      if (row < valid) {
        const size_t rbase = (size_t)(base + m0 + row) * NH;
#pragma unroll
        for (int nt = 0; nt < 4; ++nt) {
          const int col = n0 + wn + nt * 16 + l15;
          hbuf[rbase + col] = __float2bfloat16(fast_gelu(acc[mt][nt][rr] + bias[nt]));
        }
      }
    }
  }
}

// ---------------- grouped GEMM 2: out += p * (H @ w_down + b_down) ----------------
// single launch over id-tagged tile list; out zero-initialized; fp32 atomicAdd.
__global__ __launch_bounds__(512, 4) void moe_gemm_down(
    const __hip_bfloat16* __restrict__ hbuf,
    const __hip_bfloat16* __restrict__ wdnT,   // [E][D][H]
    const float* __restrict__ b_down,
    const int* __restrict__ slot_token, const float* __restrict__ slot_p,
    const int* __restrict__ cnt_ek, const int* __restrict__ off_ek,
    const int* __restrict__ ntiles, const int* __restrict__ tl_dn,
    float* __restrict__ out)
{
  if ((int)blockIdx.y >= ntiles[1]) return;
  const int tl = tl_dn[blockIdx.y];
  const int id = tl >> 16, mb = tl & 0xffff;
  const int e = id >> 1;
  const int cnt = cnt_ek[id];
  const int base = off_ek[id];
  const int m0 = mb * TM;
  const int n0 = blockIdx.x * TN;
  const int valid = (cnt - m0 < TM) ? (cnt - m0) : TM;

  __shared__ __align__(16) __hip_bfloat16 As[TM * BK];
  __shared__ __align__(16) __hip_bfloat16 Bs[TN * BK];

  const int tid = threadIdx.x;
  const int lane = tid & 63, wv = tid >> 6;

  const int raA = tid >> 2;
  const int kcA = ((tid & 3) ^ ((raA >> 1) & 3)) * 8;
  int srA = m0 + raA; if (srA >= cnt) srA = cnt - 1;
  const __hip_bfloat16* ga = hbuf + (size_t)(base + srA) * NH + kcA;
  const __hip_bfloat16* gb[2];
#pragma unroll
  for (int j = 0; j < 2; ++j) {
    const int ci = tid + 512 * j;
    const int row = ci >> 2;
    const int kc = ((ci & 3) ^ ((row >> 1) & 3)) * 8;
    gb[j] = wdnT + ((size_t)e * ND + n0 + row) * NH + kc;
  }
  char* lA = (char*)As + tid * 16;
  char* lB = (char*)Bs + tid * 16;

  const int wm = (wv >> 2) * 64, wn = (wv & 3) * 64;
  const int l15 = lane & 15, q = lane >> 4;
  const int ssw = (q ^ ((l15 >> 1) & 3)) * 16;
  const char* rA = (const char*)As + (wm + l15) * 64 + ssw;
  const char* rB = (const char*)Bs + (wn + l15) * 64 + ssw;

  f32x4 acc[4][4] = {};

  for (int kk = 0; kk < NH; kk += BK) {
    __syncthreads();
    gl_lds16(ga + kk, lA);
    gl_lds16(gb[0] + kk, lB);
    gl_lds16(gb[1] + kk, lB + 8192);
    __syncthreads();
    short8 af[4], bfr[4];
#pragma unroll
    for (int i = 0; i < 4; ++i) af[i]  = *(const short8*)(rA + i * 1024);
#pragma unroll
    for (int i = 0; i < 4; ++i) bfr[i] = *(const short8*)(rB + i * 1024);
#pragma unroll
    for (int mt = 0; mt < 4; ++mt)
#pragma unroll
      for (int nt = 0; nt < 4; ++nt)
        acc[mt][nt] = __builtin_amdgcn_mfma_f32_16x16x32_bf16(af[mt], bfr[nt], acc[mt][nt], 0, 0, 0);
  }

  float bias[4];
#pragma unroll
  for (int nt = 0; nt < 4; ++nt) bias[nt] = b_down[e * ND + n0 + wn + nt * 16 + l15];
#pragma unroll
  for (int mt = 0; mt < 4; ++mt) {
#pragma unroll
    for (int rr = 0; rr < 4; ++rr) {
      const int row = wm + mt * 16 + q * 4 + rr;
      if (row < valid) {
        const int slot = base + m0 + row;
        const int tok = slot_token[slot];
        const float p = slot_p[slot];
        const size_t obase = (size_t)tok * ND;
#pragma unroll
        for (int nt = 0; nt < 4; ++nt) {
          const int col = n0 + wn + nt * 16 + l15;
          atomicAdd(&out[obase + col], (acc[mt][nt][rr] + bias[nt]) * p);
        }
      }
    }
  }
}

// ---------------- launch ----------------
extern "C" void kernel_launch(void* const* d_in, const int* in_sizes, int n_in,
                              void* d_out, int out_size, void* d_ws, size_t ws_size,
                              hipStream_t stream) {
  (void)in_sizes; (void)n_in; (void)out_size; (void)ws_size;
  const float* x   = (const float*)d_in[0];
  const float* rw  = (const float*)d_in[1];
  const float* rb  = (const float*)d_in[2];
  const float* wup = (const float*)d_in[3];
  const float* bup = (const float*)d_in[4];
  const float* wdn = (const float*)d_in[5];
  const float* bdn = (const float*)d_in[6];
  float* out = (float*)d_out;

  char* ws = (char*)d_ws;
  __hip_bfloat16* xbf  = (__hip_bfloat16*)(ws + O_XBF);
  __hip_bfloat16* wupT = (__hip_bfloat16*)(ws + O_WUPT);
  __hip_bfloat16* wdnT = (__hip_bfloat16*)(ws + O_WDNT);
  __hip_bfloat16* hbuf = (__hip_bfloat16*)(ws + O_HBUF);
  int*   slot_token = (int*)(ws + O_STOK);
  float* slot_p     = (float*)(ws + O_SP);
  int*   topk_e     = (int*)(ws + O_TKE);
  float* topk_p     = (float*)(ws + O_TKP);
  int*   cnt_ek  = (int*)(ws + O_CTRL);
  int*   fill_ek = (int*)(ws + O_CTRL + 64);
  float* probsum = (float*)(ws + O_CTRL + 128);
  int*   off_ek  = (int*)(ws + O_CTRL + 192);
  int*   ntiles  = (int*)(ws + O_CTRL + 256);
  int*   tl_up   = (int*)(ws + O_TLUP);
  int*   tl_dn   = (int*)(ws + O_TLDN);

  hipMemsetAsync(ws + O_CTRL, 0, 272, stream);
  hipMemsetAsync(out, 0, (size_t)NT * ND * sizeof(float), stream);  // down-GEMM atomicAdd target

  // weight transposes (independent of router)
  moe_transpose_cast<<<dim3(NH / 64, ND / 64, NE), 256, 0, stream>>>(wup, wupT, ND, NH);
  moe_transpose_cast<<<dim3(ND / 64, NH / 64, NE), 256, 0, stream>>>(wdn, wdnT, NH, ND);

  // router (+ x->bf16), aux/offsets/tile-lists, scatter
  moe_router<<<256, 256, 0, stream>>>(x, rw, rb, xbf, out + (size_t)NT * ND + 1,
                                      topk_e, topk_p, cnt_ek, probsum);
  moe_finalize<<<1, 64, 0, stream>>>(cnt_ek, off_ek, probsum, out + (size_t)NT * ND,
                                     ntiles, tl_up, tl_dn);
  moe_scatter<<<NT / 256, 256, 0, stream>>>(topk_e, topk_p, off_ek, fill_ek, slot_token, slot_p);

  // grouped GEMMs (exact tile-list grids; blocks early-exit past device-side tile counts)
  moe_gemm_up<<<dim3(NH / TN, 136, 1), 512, 0, stream>>>(
      xbf, wupT, bup, slot_token, cnt_ek, off_ek, ntiles, tl_up, hbuf);
  moe_gemm_down<<<dim3(ND / TN, 144, 1), 512, 0, stream>>>(
      hbuf, wdnT, bdn, slot_token, slot_p, cnt_ek, off_ek, ntiles, tl_dn, out);
}